// Round 6
// baseline (259.550 us; speedup 1.0000x reference)
//
#include <hip/hip_runtime.h>
#include <hip/hip_cooperative_groups.h>
#include <math.h>

namespace cg = cooperative_groups;

#define BB 4
#define CC 256
#define NN 4096
#define KK 32
#define DD 256
#define GG 8    // C/K
#define NT2 64  // n-tiles of 64 in dist phase
#define NE 8    // n-eighths in the two GEMM phases

__device__ __forceinline__ float wredsum(float v) {
#pragma unroll
  for (int o = 32; o > 0; o >>= 1) v += __shfl_xor(v, o, 64);
  return v;
}

// One cooperative kernel, grid = 256 blocks x 512 threads (1 block/CU).
// Phases A..F separated by grid.sync().
__global__ __launch_bounds__(512) void k_mega(
    const float* __restrict__ x, const float* __restrict__ wth,
    const float* __restrict__ wphi, const float* __restrict__ scale,
    float* __restrict__ zout, float* __restrict__ qout,
    float* __restrict__ phi, float* __restrict__ Sp, float* __restrict__ m1e,
    float* __restrict__ code, float* __restrict__ bc2, float* __restrict__ s2g,
    float* __restrict__ t3, float* __restrict__ qpart,
    float* __restrict__ znq8) {
  cg::grid_group grid = cg::this_grid();
  const int bid = blockIdx.x;   // 0..255
  const int tid = threadIdx.x;  // 0..511
  __shared__ float smem[9600];  // 38.4 KB, reused per phase
  __shared__ float rb[8];

  // ---- Phase A: phi = exp(grouped conv) unnormalized + Sp partials ----
  {
    const int half = bid & 1, k = (bid >> 1) & 31, b = bid >> 6;
    const int n = half * 2048 + tid * 4;
    const float* xb = x + (size_t)(b * CC + k * GG) * NN + n;
    float w[GG];
#pragma unroll
    for (int j = 0; j < GG; ++j) w[j] = wphi[k * GG + j];
    float4 s = make_float4(0.f, 0.f, 0.f, 0.f);
#pragma unroll
    for (int j = 0; j < GG; ++j) {
      const float4 xv = *reinterpret_cast<const float4*>(xb + (size_t)j * NN);
      s.x = fmaf(xv.x, w[j], s.x);
      s.y = fmaf(xv.y, w[j], s.y);
      s.z = fmaf(xv.z, w[j], s.z);
      s.w = fmaf(xv.w, w[j], s.w);
    }
    float4 e4;
    e4.x = __expf(s.x); e4.y = __expf(s.y);
    e4.z = __expf(s.z); e4.w = __expf(s.w);
    *reinterpret_cast<float4*>(phi + (size_t)(b * KK + k) * NN + n) = e4;
    float sum = wredsum(e4.x + e4.y + e4.z + e4.w);
    if ((tid & 63) == 0) rb[tid >> 6] = sum;
    __syncthreads();
    if (tid == 0) {
      float t = 0.f;
#pragma unroll
      for (int i = 0; i < 8; ++i) t += rb[i];
      Sp[((size_t)half * BB + b) * KK + k] = t;
    }
  }
  grid.sync();

  // ---- Phase B: m1e[e][b][k][c] = sum_{n in eighth} x[c,n] * phi[k,n] ----
  {
    const int b = bid >> 6, e = (bid >> 3) & 7, ct = bid & 7;
    const int k = tid & 31, g = tid >> 5;    // compute roles (g 0..15)
    const int kl = tid >> 4, nq = tid & 15;  // staging roles
    float acc[32];
#pragma unroll
    for (int c = 0; c < 32; ++c) acc[c] = 0.f;
    const int ne0 = e * 512;
    const float* xbase = x + (size_t)(b * CC + ct * 32) * NN;
#pragma unroll
    for (int ch = 0; ch < 2; ++ch) {
      const int n0 = ne0 + ch * 256;
      const float* pk = phi + (size_t)(b * KK + kl) * NN + n0 + nq * 16;
#pragma unroll
      for (int j = 0; j < 4; ++j) {
        const float4 pv = *reinterpret_cast<const float4*>(pk + j * 4);
        const int nn = nq * 16 + j * 4;
        smem[(nn + 0) * 33 + kl] = pv.x;
        smem[(nn + 1) * 33 + kl] = pv.y;
        smem[(nn + 2) * 33 + kl] = pv.z;
        smem[(nn + 3) * 33 + kl] = pv.w;
      }
      __syncthreads();
      float ph[16];
#pragma unroll
      for (int i = 0; i < 16; ++i) ph[i] = smem[(g * 16 + i) * 33 + k];
#pragma unroll
      for (int c = 0; c < 32; ++c) {
        const float* xr = xbase + (size_t)c * NN + n0 + g * 16;
#pragma unroll
        for (int j = 0; j < 4; ++j) {
          const float4 xv = *reinterpret_cast<const float4*>(xr + j * 4);
          acc[c] = fmaf(xv.x, ph[j * 4 + 0], acc[c]);
          acc[c] = fmaf(xv.y, ph[j * 4 + 1], acc[c]);
          acc[c] = fmaf(xv.z, ph[j * 4 + 2], acc[c]);
          acc[c] = fmaf(xv.w, ph[j * 4 + 3], acc[c]);
        }
      }
      __syncthreads();
    }
    // two-step cross-g reduce (g>=8 write, g<8 add)
    if (g >= 8) {
#pragma unroll
      for (int c = 0; c < 32; ++c) smem[((g - 8) * 32 + c) * 33 + k] = acc[c];
    }
    __syncthreads();
    if (g < 8) {
#pragma unroll
      for (int c = 0; c < 32; ++c) smem[(g * 32 + c) * 33 + k] += acc[c];
    }
    __syncthreads();
#pragma unroll
    for (int o = 0; o < 2; ++o) {
      const int idx = o * 512 + tid;
      const int c2 = idx >> 5, k2 = idx & 31;
      float s = 0.f;
#pragma unroll
      for (int gg = 0; gg < 8; ++gg) s += smem[(gg * 32 + c2) * 33 + k2];
      m1e[((size_t)(e * BB + b) * KK + k2) * CC + ct * 32 + c2] = s;
    }
  }
  grid.sync();

  // ---- Phase C: code/bc2/s2g/t3 (128 active blocks, 256 active threads) ----
  {
    const bool blkact = bid < 128;
    const int b = (bid >> 5) & 3, k = bid & 31;
    const bool act = blkact && (tid < 256);
    const int d = tid;
    if (act) {
      const float invS =
          1.f / (Sp[(size_t)b * KK + k] + Sp[((size_t)BB + b) * KK + k]);
      float m = 0.f;
#pragma unroll
      for (int e = 0; e < NE; ++e)
        m += m1e[((size_t)(e * BB + b) * KK + k) * CC + d];
      smem[d] = m * invS;
    }
    __syncthreads();
    float cd = 0.f;
    if (act) {
      const float* wt = wth + (size_t)d * CC;
#pragma unroll 4
      for (int c = 0; c < CC; c += 4) {
        const float4 w4 = *reinterpret_cast<const float4*>(wt + c);
        cd = fmaf(w4.x, smem[c + 0], cd);
        cd = fmaf(w4.y, smem[c + 1], cd);
        cd = fmaf(w4.z, smem[c + 2], cd);
        cd = fmaf(w4.w, smem[c + 3], cd);
      }
    }
    float ss = wredsum(act ? cd * cd : 0.f);
    if ((tid & 63) == 0) rb[tid >> 6] = ss;
    __syncthreads();
    float nr2 = 0.f;
#pragma unroll
    for (int i = 0; i < 8; ++i) nr2 += rb[i];
    const float inv = 1.f / fmaxf(sqrtf(nr2), 1e-12f);
    float tt = 0.f;
    if (act) {
      cd *= inv;
      const float sc = scale[(size_t)d * KK + k];
      const float s2 = sc * sc;
      code[((size_t)b * DD + d) * KK + k] = cd;
      bc2[((size_t)b * DD + d) * KK + k] = 2.f * s2 * cd;
      if (b == 0) s2g[(size_t)d * KK + k] = s2;
      tt = s2 * cd * cd;
    }
    float t2 = wredsum(tt);
    __syncthreads();
    if ((tid & 63) == 0) rb[tid >> 6] = t2;
    __syncthreads();
    if (blkact && tid == 0) {
      float t = 0.f;
#pragma unroll
      for (int i = 0; i < 8; ++i) t += rb[i];
      t3[b * KK + k] = t;
    }
  }
  grid.sync();

  // ---- Phase D: dist + softmax(k) -> Q + qpart ----
  {
    float* lds = smem;          // 4*64*33 = 8448
    float* smax = smem + 8448;  // 64*9 = 576
    float* ssum = smem + 9024;  // 64*9 = 576
    const int b = bid >> 6;
    const int tile = bid & 63;
    const int n0 = tile * 64;
    const int lane = tid & 63;
    const int wid = __builtin_amdgcn_readfirstlane(tid >> 6);  // 0..7
    const int d0 = wid * 32;
    float accA[32], accB[32];
#pragma unroll
    for (int k = 0; k < 32; ++k) { accA[k] = 0.f; accB[k] = 0.f; }
    const float* xb = x + ((size_t)b * CC + d0) * NN + n0 + lane;
    const float* s2b = s2g + (size_t)d0 * KK;
    const float* bcb = bc2 + ((size_t)b * DD + d0) * KK;
#pragma unroll 2
    for (int dd = 0; dd < 32; ++dd) {
      const float xv = xb[(size_t)dd * NN];
      const float x2 = xv * xv;
      const float* s2r = s2b + dd * KK;
      const float* bcr = bcb + dd * KK;
#pragma unroll
      for (int k = 0; k < 32; ++k) {
        accA[k] = fmaf(x2, s2r[k], accA[k]);
        accB[k] = fmaf(xv, bcr[k], accB[k]);
      }
    }
    if (wid >= 4) {
      float* Lp = lds + ((size_t)((wid - 4) * 64 + lane)) * 33;
#pragma unroll
      for (int k = 0; k < 32; ++k) Lp[k] = accA[k] - accB[k];
    }
    __syncthreads();
    if (wid < 4) {
      float* Lp = lds + ((size_t)(wid * 64 + lane)) * 33;
#pragma unroll
      for (int k = 0; k < 32; ++k) Lp[k] += accA[k] - accB[k];
    }
    __syncthreads();
    const int n = lane;
    const int kq = wid;
    float vals[4];
#pragma unroll
    for (int j = 0; j < 4; ++j) {
      const int k = kq * 4 + j;
      float s = 0.f;
#pragma unroll
      for (int g = 0; g < 4; ++g) s += lds[((size_t)(g * 64 + n)) * 33 + k];
      vals[j] = -0.5f * (s + t3[b * KK + k]);
    }
    float m4 = fmaxf(fmaxf(vals[0], vals[1]), fmaxf(vals[2], vals[3]));
    smax[n * 9 + kq] = m4;
    __syncthreads();
    float m = smax[n * 9 + 0];
#pragma unroll
    for (int g = 1; g < 8; ++g) m = fmaxf(m, smax[n * 9 + g]);
    float e[4];
    float ps = 0.f;
#pragma unroll
    for (int j = 0; j < 4; ++j) {
      e[j] = __expf(vals[j] - m);
      ps += e[j];
    }
    ssum[n * 9 + kq] = ps;
    __syncthreads();
    float tot = 0.f;
#pragma unroll
    for (int g = 0; g < 8; ++g) tot += ssum[n * 9 + g];
    const float inv = 1.f / tot;
    float4 q4;
    q4.x = e[0] * inv; q4.y = e[1] * inv;
    q4.z = e[2] * inv; q4.w = e[3] * inv;
    *reinterpret_cast<float4*>(qout + ((size_t)b * NN + n0 + n) * KK + kq * 4) =
        q4;
    float qs[4] = {q4.x, q4.y, q4.z, q4.w};
#pragma unroll
    for (int j = 0; j < 4; ++j) {
      const float v = wredsum(qs[j]);
      if (n == 0) qpart[((size_t)b * KK + kq * 4 + j) * NT2 + tile] = v;
    }
  }
  grid.sync();

  // ---- Phase E: znq8[e][b][k][c] = sum_{n in eighth} x[c,n] * Q[n,k] ----
  {
    const int b = bid >> 6, e = (bid >> 3) & 7, ct = bid & 7;
    const int k = tid & 31, g = tid >> 5;
    float acc[32];
#pragma unroll
    for (int c = 0; c < 32; ++c) acc[c] = 0.f;
    const int ne0 = e * 512;
    const float* xbase = x + (size_t)(b * CC + ct * 32) * NN;
#pragma unroll
    for (int ch = 0; ch < 2; ++ch) {
      const int n0 = ne0 + ch * 256;
      const int r = tid >> 1, ko = (tid & 1) * 16;
      const float* qr = qout + ((size_t)b * NN + n0 + r) * KK + ko;
#pragma unroll
      for (int j = 0; j < 4; ++j) {
        const float4 qv = *reinterpret_cast<const float4*>(qr + j * 4);
        const int kk = ko + j * 4;
        smem[r * 33 + kk + 0] = qv.x;
        smem[r * 33 + kk + 1] = qv.y;
        smem[r * 33 + kk + 2] = qv.z;
        smem[r * 33 + kk + 3] = qv.w;
      }
      __syncthreads();
      float ph[16];
#pragma unroll
      for (int i = 0; i < 16; ++i) ph[i] = smem[(g * 16 + i) * 33 + k];
#pragma unroll
      for (int c = 0; c < 32; ++c) {
        const float* xr = xbase + (size_t)c * NN + n0 + g * 16;
#pragma unroll
        for (int j = 0; j < 4; ++j) {
          const float4 xv = *reinterpret_cast<const float4*>(xr + j * 4);
          acc[c] = fmaf(xv.x, ph[j * 4 + 0], acc[c]);
          acc[c] = fmaf(xv.y, ph[j * 4 + 1], acc[c]);
          acc[c] = fmaf(xv.z, ph[j * 4 + 2], acc[c]);
          acc[c] = fmaf(xv.w, ph[j * 4 + 3], acc[c]);
        }
      }
      __syncthreads();
    }
    if (g >= 8) {
#pragma unroll
      for (int c = 0; c < 32; ++c) smem[((g - 8) * 32 + c) * 33 + k] = acc[c];
    }
    __syncthreads();
    if (g < 8) {
#pragma unroll
      for (int c = 0; c < 32; ++c) smem[(g * 32 + c) * 33 + k] += acc[c];
    }
    __syncthreads();
#pragma unroll
    for (int o = 0; o < 2; ++o) {
      const int idx = o * 512 + tid;
      const int c2 = idx >> 5, k2 = idx & 31;
      float s = 0.f;
#pragma unroll
      for (int gg = 0; gg < 8; ++gg) s += smem[(gg * 32 + c2) * 33 + k2];
      znq8[((size_t)(e * BB + b) * KK + k2) * CC + ct * 32 + c2] = s;
    }
  }
  grid.sync();

  // ---- Phase F: Qsum + Z (128 active blocks, 256 active threads) ----
  {
    const bool blkact = bid < 128;
    const int b = (bid >> 5) & 3, k = bid & 31;
    const bool act = blkact && (tid < 256);
    const int d = tid;
    float qp = (blkact && tid < NT2)
                   ? qpart[((size_t)b * KK + k) * NT2 + tid]
                   : 0.f;
    float qpw = wredsum(qp);
    if ((tid & 63) == 0) rb[tid >> 6] = qpw;
    __syncthreads();
    float qs = 0.f;
#pragma unroll
    for (int i = 0; i < 8; ++i) qs += rb[i];
    float z_ = 0.f;
    if (act) {
      float zn = 0.f;
#pragma unroll
      for (int e = 0; e < NE; ++e)
        zn += znq8[((size_t)(e * BB + b) * KK + k) * CC + d];
      const float cdv = code[((size_t)b * DD + d) * KK + k];
      z_ = scale[(size_t)d * KK + k] * (zn / qs - cdv);
    }
    float ss = wredsum(act ? z_ * z_ : 0.f);
    __syncthreads();
    if ((tid & 63) == 0) rb[tid >> 6] = ss;
    __syncthreads();
    if (act) {
      float t = 0.f;
#pragma unroll
      for (int i = 0; i < 8; ++i) t += rb[i];
      zout[((size_t)b * DD + d) * KK + k] = z_ * (1.f / sqrtf(t));
    }
  }
}

extern "C" void kernel_launch(void* const* d_in, const int* in_sizes, int n_in,
                              void* d_out, int out_size, void* d_ws,
                              size_t ws_size, hipStream_t stream) {
  const float* x = (const float*)d_in[0];
  const float* wth = (const float*)d_in[1];
  const float* wphi = (const float*)d_in[2];
  const float* scale = (const float*)d_in[3];
  float* out = (float*)d_out;
  float* zout = out;                         // B*D*K = 32768
  float* qout = out + (size_t)BB * DD * KK;  // B*N*K = 524288
  float* ws = (float*)d_ws;
  float* phi = ws;                                // B*K*N   = 524288
  float* Sp = phi + (size_t)BB * NN * KK;         // 2*B*K   = 256
  float* m1e = Sp + 2 * (size_t)BB * KK;          // 8*B*K*C = 262144
  float* code = m1e + (size_t)NE * BB * KK * CC;  // B*D*K   = 32768
  float* bc2 = code + (size_t)BB * DD * KK;       // B*D*K   = 32768
  float* s2g = bc2 + (size_t)BB * DD * KK;        // D*K     = 8192
  float* t3 = s2g + (size_t)DD * KK;              // B*K     = 128
  float* qpart = t3 + BB * KK;                    // B*K*64  = 8192
  float* znq8 = qpart + (size_t)BB * KK * NT2;    // 8*B*K*C = 262144

  void* args[] = {&x,    &wth, &wphi, &scale, &zout, &qout, &phi,  &Sp,
                  &m1e,  &code, &bc2,  &s2g,   &t3,   &qpart, &znq8};
  hipLaunchCooperativeKernel((const void*)k_mega, dim3(256), dim3(512), args,
                             0, stream);
}

// Round 7
// 91.850 us; speedup vs baseline: 2.8258x; 2.8258x over previous
//
#include <hip/hip_runtime.h>
#include <math.h>

#define BB 4
#define CC 256
#define NN 4096
#define KK 32
#define DD 256
#define GG 8    // C/K
#define NEs 64  // n-slices of 64 (k_pm1, k_distq tiles)

__device__ __forceinline__ float wredsum(float v) {
#pragma unroll
  for (int o = 32; o > 0; o >>= 1) v += __shfl_xor(v, o, 64);
  return v;
}

// Kernel 1: fused phi (grouped conv + exp, LDS-only) + m1 partials.
// grid = B*64 (64-n slices), block 512.
// Outputs: m1e[e][b][k][c] (unnormalized), SpE[e][b][k] (exp-sum partials).
__global__ __launch_bounds__(512) void k_pm1(const float* __restrict__ x,
                                             const float* __restrict__ wphi,
                                             float* __restrict__ m1e,
                                             float* __restrict__ SpE) {
  const int b = blockIdx.x >> 6;
  const int e = blockIdx.x & 63;
  const int n0 = e * 64;
  const int tid = threadIdx.x;
  __shared__ float phis[32 * 65];  // phi[k][n], stride 65 (bank-spread)
  __shared__ float tr[256 * 33];   // transpose buffer
  // --- conv + exp into LDS ---
  {
    const int kk = tid >> 4;        // 0..31
    const int m = tid & 15;         // n4 = m*4
    const float* xb = x + (size_t)(b * CC + kk * GG) * NN + n0 + m * 4;
    float w[GG];
#pragma unroll
    for (int j = 0; j < GG; ++j) w[j] = wphi[kk * GG + j];
    float4 s = make_float4(0.f, 0.f, 0.f, 0.f);
#pragma unroll
    for (int j = 0; j < GG; ++j) {
      const float4 xv = *reinterpret_cast<const float4*>(xb + (size_t)j * NN);
      s.x = fmaf(xv.x, w[j], s.x);
      s.y = fmaf(xv.y, w[j], s.y);
      s.z = fmaf(xv.z, w[j], s.z);
      s.w = fmaf(xv.w, w[j], s.w);
    }
    float* pr = phis + kk * 65 + m * 4;
    pr[0] = __expf(s.x);
    pr[1] = __expf(s.y);
    pr[2] = __expf(s.z);
    pr[3] = __expf(s.w);
  }
  __syncthreads();
  // --- Sp partials (32 threads) ---
  if (tid < 32) {
    float s = 0.f;
#pragma unroll 8
    for (int n = 0; n < 64; ++n) s += phis[tid * 65 + n];
    SpE[((size_t)e * BB + b) * KK + tid] = s;
  }
  // --- m1: thread (k = tid&31, ct = tid>>5 -> 16 c's) ---
  const int k = tid & 31;
  const int ct = tid >> 5;
  float acc[16];
#pragma unroll
  for (int c = 0; c < 16; ++c) acc[c] = 0.f;
  const float* xm = x + (size_t)(b * CC + ct * 16) * NN + n0;
#pragma unroll
  for (int sub = 0; sub < 4; ++sub) {
    float ph[16];
#pragma unroll
    for (int i = 0; i < 16; ++i) ph[i] = phis[k * 65 + sub * 16 + i];
#pragma unroll
    for (int c = 0; c < 16; ++c) {
      const float* xr = xm + (size_t)c * NN + sub * 16;
#pragma unroll
      for (int n4 = 0; n4 < 4; ++n4) {
        const float4 xv = *reinterpret_cast<const float4*>(xr + n4 * 4);
        acc[c] = fmaf(xv.x, ph[n4 * 4 + 0], acc[c]);
        acc[c] = fmaf(xv.y, ph[n4 * 4 + 1], acc[c]);
        acc[c] = fmaf(xv.z, ph[n4 * 4 + 2], acc[c]);
        acc[c] = fmaf(xv.w, ph[n4 * 4 + 3], acc[c]);
      }
    }
  }
#pragma unroll
  for (int i = 0; i < 16; ++i) tr[(ct * 16 + i) * 33 + k] = acc[i];
  __syncthreads();
  float* mb = m1e + ((size_t)e * BB + b) * KK * CC;
#pragma unroll
  for (int o = 0; o < 16; ++o) {
    const int idx = o * 512 + tid;
    const int c2 = idx & 255, k2 = idx >> 8;
    mb[(size_t)k2 * CC + c2] = tr[c2 * 33 + k2];
  }
}

// Kernel 2: M1 = (sum_e m1e)/S; code = w_theta @ M1 normalized over d;
// emit code, bc2 = 2*s2*code, s2, t3. grid = B*K, block 256.
__global__ __launch_bounds__(256) void k_code(const float* __restrict__ m1e,
                                              const float* __restrict__ SpE,
                                              const float* __restrict__ wth,
                                              const float* __restrict__ scale,
                                              float* __restrict__ code,
                                              float* __restrict__ bc2,
                                              float* __restrict__ s2g,
                                              float* __restrict__ t3) {
  const int b = blockIdx.x >> 5;
  const int k = blockIdx.x & 31;
  const int d = threadIdx.x;
  __shared__ __align__(16) float m1s[CC];
  __shared__ float rb[4];
  // total exp-sum S
  float sp = (d < NEs) ? SpE[((size_t)d * BB + b) * KK + k] : 0.f;
  sp = wredsum(sp);
  if ((d & 63) == 0) rb[d >> 6] = sp;
  __syncthreads();
  const float invS = 1.f / (rb[0] + rb[1] + rb[2] + rb[3]);
  float m = 0.f;
  for (int e = 0; e < NEs; ++e)
    m += m1e[(((size_t)e * BB + b) * KK + k) * CC + d];
  m1s[d] = m * invS;
  __syncthreads();
  float cd = 0.f;
  const float* wt = wth + (size_t)d * CC;
#pragma unroll 4
  for (int c = 0; c < CC; c += 4) {
    const float4 w4 = *reinterpret_cast<const float4*>(wt + c);
    const float4 m4 = *reinterpret_cast<const float4*>(&m1s[c]);
    cd = fmaf(w4.x, m4.x, cd);
    cd = fmaf(w4.y, m4.y, cd);
    cd = fmaf(w4.z, m4.z, cd);
    cd = fmaf(w4.w, m4.w, cd);
  }
  float ss = wredsum(cd * cd);
  __syncthreads();
  if ((d & 63) == 0) rb[d >> 6] = ss;
  __syncthreads();
  const float nrm = sqrtf(rb[0] + rb[1] + rb[2] + rb[3]);
  const float inv = 1.f / fmaxf(nrm, 1e-12f);
  cd *= inv;
  const float sc = scale[(size_t)d * KK + k];
  const float s2 = sc * sc;
  code[((size_t)b * DD + d) * KK + k] = cd;
  bc2[((size_t)b * DD + d) * KK + k] = 2.f * s2 * cd;
  if (b == 0) s2g[(size_t)d * KK + k] = s2;
  float tt = wredsum(s2 * cd * cd);
  __syncthreads();
  if ((d & 63) == 0) rb[d >> 6] = tt;
  __syncthreads();
  if (d == 0) t3[b * KK + k] = rb[0] + rb[1] + rb[2] + rb[3];
}

// Kernel 3: dist + softmax(k) -> Q (d_out) + qpart + fused Znum tile-partials.
// grid = B*64 (64-n tiles), block 512 (8 waves).
// znt layout [b][t][k][c].
__global__ __launch_bounds__(512) void k_distq(const float* __restrict__ x,
                                               const float* __restrict__ s2g,
                                               const float* __restrict__ bc2,
                                               const float* __restrict__ t3,
                                               float* __restrict__ qout,
                                               float* __restrict__ qpart,
                                               float* __restrict__ znt) {
  const int b = blockIdx.x >> 6;
  const int tile = blockIdx.x & 63;
  const int n0 = tile * 64;
  const int tid = threadIdx.x;
  const int lane = tid & 63;
  const int wid = __builtin_amdgcn_readfirstlane(tid >> 6);  // 0..7
  const int d0 = wid * 32;
  __shared__ float lds[4 * 64 * 33];  // 8448, reused as transpose buf
  __shared__ float smax[64 * 9];
  __shared__ float ssum[64 * 9];
  __shared__ float qlds[64 * 33];
  // --- phase 1: dist partials (wave-uniform scalar s2/bc2) ---
  float accA[32], accB[32];
#pragma unroll
  for (int k = 0; k < 32; ++k) { accA[k] = 0.f; accB[k] = 0.f; }
  {
    const float* xb = x + ((size_t)b * CC + d0) * NN + n0 + lane;
    const float* s2b = s2g + (size_t)d0 * KK;
    const float* bcb = bc2 + ((size_t)b * DD + d0) * KK;
#pragma unroll 2
    for (int dd = 0; dd < 32; ++dd) {
      const float xv = xb[(size_t)dd * NN];
      const float x2 = xv * xv;
      const float* s2r = s2b + dd * KK;
      const float* bcr = bcb + dd * KK;
#pragma unroll
      for (int k = 0; k < 32; ++k) {
        accA[k] = fmaf(x2, s2r[k], accA[k]);
        accB[k] = fmaf(xv, bcr[k], accB[k]);
      }
    }
  }
  if (wid >= 4) {
    float* Lp = lds + ((size_t)((wid - 4) * 64 + lane)) * 33;
#pragma unroll
    for (int k = 0; k < 32; ++k) Lp[k] = accA[k] - accB[k];
  }
  __syncthreads();
  if (wid < 4) {
    float* Lp = lds + ((size_t)(wid * 64 + lane)) * 33;
#pragma unroll
    for (int k = 0; k < 32; ++k) Lp[k] += accA[k] - accB[k];
  }
  __syncthreads();
  // --- phase 2: softmax over k ---
  {
    const int n = lane;
    const int kq = wid;
    float vals[4];
#pragma unroll
    for (int j = 0; j < 4; ++j) {
      const int k = kq * 4 + j;
      float s = 0.f;
#pragma unroll
      for (int g = 0; g < 4; ++g) s += lds[((size_t)(g * 64 + n)) * 33 + k];
      vals[j] = -0.5f * (s + t3[b * KK + k]);
    }
    float m4 = fmaxf(fmaxf(vals[0], vals[1]), fmaxf(vals[2], vals[3]));
    smax[n * 9 + kq] = m4;
    __syncthreads();
    float m = smax[n * 9 + 0];
#pragma unroll
    for (int g = 1; g < 8; ++g) m = fmaxf(m, smax[n * 9 + g]);
    float e[4];
    float ps = 0.f;
#pragma unroll
    for (int j = 0; j < 4; ++j) {
      e[j] = __expf(vals[j] - m);
      ps += e[j];
    }
    ssum[n * 9 + kq] = ps;
    __syncthreads();
    float tot = 0.f;
#pragma unroll
    for (int g = 0; g < 8; ++g) tot += ssum[n * 9 + g];
    const float inv = 1.f / tot;
    float4 q4;
    q4.x = e[0] * inv; q4.y = e[1] * inv;
    q4.z = e[2] * inv; q4.w = e[3] * inv;
    *reinterpret_cast<float4*>(qout + ((size_t)b * NN + n0 + n) * KK + kq * 4) =
        q4;
    float* qr = qlds + n * 33 + kq * 4;
    qr[0] = q4.x; qr[1] = q4.y; qr[2] = q4.z; qr[3] = q4.w;
    float qs[4] = {q4.x, q4.y, q4.z, q4.w};
#pragma unroll
    for (int j = 0; j < 4; ++j) {
      const float v = wredsum(qs[j]);
      if (n == 0) qpart[((size_t)b * KK + kq * 4 + j) * NEs + tile] = v;
    }
  }
  __syncthreads();
  // --- phase 3: znt[b][t][k][c] = sum_n x[c,n] * Q[n,k] ---
  {
    const int k = tid & 31;
    const int ct = tid >> 5;  // 16 chunks of 16 c
    float acc[16];
#pragma unroll
    for (int c = 0; c < 16; ++c) acc[c] = 0.f;
    const float* xq = x + (size_t)(b * CC + ct * 16) * NN + n0;
#pragma unroll
    for (int sub = 0; sub < 4; ++sub) {
      float qq[16];
#pragma unroll
      for (int i = 0; i < 16; ++i) qq[i] = qlds[(sub * 16 + i) * 33 + k];
#pragma unroll
      for (int c = 0; c < 16; ++c) {
        const float* xr = xq + (size_t)c * NN + sub * 16;
#pragma unroll
        for (int n4 = 0; n4 < 4; ++n4) {
          const float4 xv = *reinterpret_cast<const float4*>(xr + n4 * 4);
          acc[c] = fmaf(xv.x, qq[n4 * 4 + 0], acc[c]);
          acc[c] = fmaf(xv.y, qq[n4 * 4 + 1], acc[c]);
          acc[c] = fmaf(xv.z, qq[n4 * 4 + 2], acc[c]);
          acc[c] = fmaf(xv.w, qq[n4 * 4 + 3], acc[c]);
        }
      }
    }
#pragma unroll
    for (int i = 0; i < 16; ++i) lds[(ct * 16 + i) * 33 + k] = acc[i];
    __syncthreads();
    float* zb = znt + ((size_t)b * NEs + tile) * KK * CC;
#pragma unroll
    for (int o = 0; o < 16; ++o) {
      const int idx = o * 512 + tid;
      const int c2 = idx & 255, k2 = idx >> 8;
      zb[(size_t)k2 * CC + c2] = lds[c2 * 33 + k2];
    }
  }
}

// Kernel 4: Qsum reduce + Znum t-reduce + Z = scale*(Znum/Qsum - code),
// d-normalized. grid = B*K, block 256.
__global__ __launch_bounds__(256) void k_z(const float* __restrict__ znt,
                                           const float* __restrict__ code,
                                           const float* __restrict__ scale,
                                           const float* __restrict__ qpart,
                                           float* __restrict__ zout) {
  const int b = blockIdx.x >> 5;
  const int k = blockIdx.x & 31;
  const int d = threadIdx.x;
  __shared__ float rb[4];
  float qp = (d < NEs) ? qpart[((size_t)b * KK + k) * NEs + d] : 0.f;
  qp = wredsum(qp);
  if ((d & 63) == 0) rb[d >> 6] = qp;
  __syncthreads();
  const float qs = rb[0] + rb[1] + rb[2] + rb[3];
  const float* zp = znt + ((size_t)b * NEs * KK + k) * CC + d;
  float z0 = 0.f, z1 = 0.f, z2 = 0.f, z3 = 0.f;
  const size_t tstr = (size_t)KK * CC;
  for (int t = 0; t < NEs; t += 4) {
    z0 += zp[(size_t)(t + 0) * tstr];
    z1 += zp[(size_t)(t + 1) * tstr];
    z2 += zp[(size_t)(t + 2) * tstr];
    z3 += zp[(size_t)(t + 3) * tstr];
  }
  const float zn = (z0 + z1) + (z2 + z3);
  const float cd = code[((size_t)b * DD + d) * KK + k];
  const float z_ = scale[(size_t)d * KK + k] * (zn / qs - cd);
  float ss = wredsum(z_ * z_);
  __syncthreads();
  if ((d & 63) == 0) rb[d >> 6] = ss;
  __syncthreads();
  const float rn = 1.f / sqrtf(rb[0] + rb[1] + rb[2] + rb[3]);
  zout[((size_t)b * DD + d) * KK + k] = z_ * rn;
}

extern "C" void kernel_launch(void* const* d_in, const int* in_sizes, int n_in,
                              void* d_out, int out_size, void* d_ws,
                              size_t ws_size, hipStream_t stream) {
  const float* x = (const float*)d_in[0];
  const float* wth = (const float*)d_in[1];
  const float* wphi = (const float*)d_in[2];
  const float* scale = (const float*)d_in[3];
  float* out = (float*)d_out;
  float* zout = out;                         // B*D*K = 32768
  float* qout = out + (size_t)BB * DD * KK;  // B*N*K = 524288
  float* ws = (float*)d_ws;
  float* SpE = ws;                                  // 64*B*K     = 8192
  float* m1e = SpE + (size_t)NEs * BB * KK;         // 64*B*K*C   = 2097152
  float* code = m1e + (size_t)NEs * BB * KK * CC;   // B*D*K      = 32768
  float* bc2 = code + (size_t)BB * DD * KK;         // B*D*K      = 32768
  float* s2g = bc2 + (size_t)BB * DD * KK;          // D*K        = 8192
  float* t3 = s2g + (size_t)DD * KK;                // B*K        = 128
  float* qpart = t3 + BB * KK;                      // B*K*64     = 8192
  float* znt = qpart + (size_t)BB * KK * NEs;       // B*64*K*C   = 2097152

  k_pm1<<<BB * NEs, 512, 0, stream>>>(x, wphi, m1e, SpE);
  k_code<<<BB * KK, 256, 0, stream>>>(m1e, SpE, wth, scale, code, bc2, s2g, t3);
  k_distq<<<BB * NEs, 512, 0, stream>>>(x, s2g, bc2, t3, qout, qpart, znt);
  k_z<<<BB * KK, 256, 0, stream>>>(znt, code, scale, qpart, zout);
}